// Round 5
// baseline (654.934 us; speedup 1.0000x reference)
//
#include <hip/hip_runtime.h>
#include <cstddef>

#define HWN 65536              // 256*256
#define SCALE 0.35355339059327373f

typedef __bf16 bf16x8_t __attribute__((ext_vector_type(8)));
typedef float  f32x4_t  __attribute__((ext_vector_type(4)));

static __device__ __forceinline__ ushort f2bf(float f) {
    uint u = __float_as_uint(f);
    u = u + 0x7fffu + ((u >> 16) & 1u);   // RNE
    return (ushort)(u >> 16);
}
static __device__ __forceinline__ float bf2f(ushort b) {
    return __uint_as_float(((uint)b) << 16);
}

// ---------------------------------------------------------------------------
// Kernel 0: expand bias_table via rel_index into MFMA C-fragment order:
// biasF[h][tile=i*4+j][lane][r] so win_attn can init its QK accumulators
// directly from 16 coalesced float4 loads (bias rides in the MFMA C input).
// ---------------------------------------------------------------------------
__global__ __launch_bounds__(256) void bias_pre(
    const float* __restrict__ bt, const int* __restrict__ ri,
    float* __restrict__ biasF)
{
    int g = blockIdx.x * 256 + threadIdx.x;   // 0..32767
    int h    = g >> 12;
    int rem  = g & 4095;
    int tile = rem >> 8;            // i*4 + j
    int lane = (rem >> 2) & 63;
    int r    = rem & 3;
    int i = tile >> 2, j = tile & 3;
    int qd = lane >> 4, ln = lane & 15;
    int m = i * 16 + qd * 4 + r;
    int n = j * 16 + ln;
    biasF[g] = bt[ri[n * 64 + m] * 8 + h];
}

// ---------------------------------------------------------------------------
// Kernel 0b: one-shot f32 -> bf16 pack of a 256x256 weight matrix (R5).
// Removes 32 f2bf VALU ops per thread per K-iter from gemm256's A-staging
// and frees VGPR budget for the staging prefetch.
// ---------------------------------------------------------------------------
__global__ __launch_bounds__(256) void pack_w(
    const float* __restrict__ Wf, ushort* __restrict__ Wb)
{
    int g = blockIdx.x * 256 + threadIdx.x;   // 16384 threads x 4 elems
    float4 v = *(const float4*)&Wf[g * 4];
    ushort4 o = make_ushort4(f2bf(v.x), f2bf(v.y), f2bf(v.z), f2bf(v.w));
    *(ushort4*)&Wb[g * 4] = o;
}

// ---------------------------------------------------------------------------
// Kernel 1: fused 1x1 conv pair (R5): qp = Wq.q, kp = Wk.qp in ONE pass.
// R4 post-mortem: two 90us dispatches, each latency-bound (2 waves/SIMD,
// 64 serial strided loads), serialized by the qp dependency, with qp
// re-read from HBM.  Fused: q read once, qp kept in registers, both
// outputs written.  Same f32 math order -> bit-identical results.
// ---------------------------------------------------------------------------
__global__ __launch_bounds__(256) void conv1x1_qk(
    const float* __restrict__ X, const float* __restrict__ WQ,
    const float* __restrict__ WK, float* __restrict__ QP,
    float* __restrict__ KP)
{
    int gp = blockIdx.x * 256 + threadIdx.x;
    int b  = gp >> 16;
    int p  = gp & 65535;
    const float* Xb = X + (size_t)b * 64 * HWN + p;
    float* Qb = QP + (size_t)b * 64 * HWN + p;
    float* Kb = KP + (size_t)b * 64 * HWN + p;

    float xr[64];
#pragma unroll
    for (int c = 0; c < 64; c++) xr[c] = Xb[(size_t)c * HWN];

    float qr[64];
#pragma unroll 4
    for (int o = 0; o < 64; o++) {
        const float* Wr = WQ + o * 64;
        float acc = 0.f;
#pragma unroll
        for (int c = 0; c < 64; c++) acc = fmaf(Wr[c], xr[c], acc);
        qr[o] = acc;
        Qb[(size_t)o * HWN] = acc;
    }

#pragma unroll 4
    for (int o = 0; o < 64; o++) {
        const float* Wr = WK + o * 64;
        float acc = 0.f;
#pragma unroll
        for (int c = 0; c < 64; c++) acc = fmaf(Wr[c], qr[c], acc);
        Kb[(size_t)o * HWN] = acc;
    }
}

// ---------------------------------------------------------------------------
// Kernel 2: 256->256 channel GEMM via bf16 MFMA.
// R5: (a) W arrives pre-packed bf16 -> A-staging is a raw uint4 copy;
//     (b) T14 async-stage split: next K-chunk's global loads are issued
//     between the two barriers, so ~900cyc HBM latency hides under the
//     MFMA phase + barrier instead of stalling the staging phase.
// ---------------------------------------------------------------------------
template <typename XT, typename YT>
__global__ __launch_bounds__(256) void gemm256(
    const XT* __restrict__ X, const ushort* __restrict__ Wb,
    YT* __restrict__ Y)
{
    __shared__ ushort Al[128 * 72];   // [m][k], stride 72 bf16
    __shared__ ushort Bl[128 * 72];   // [n][k], swizzled 16B groups

    int b   = blockIdx.z;
    int oB  = blockIdx.y * 128;
    int pB  = blockIdx.x * 128;
    int tid = threadIdx.x;

    const XT* Xb = X + (size_t)b * 256 * HWN;
    YT*       Yb = Y + (size_t)b * 256 * HWN;

    int wv = tid >> 6, lane = tid & 63;
    int wm = (wv >> 1) * 64, wn = (wv & 1) * 64;
    int qd = lane >> 4, ln = lane & 15;

    int kgB = tid >> 4;
    int pgB = tid & 15;
    int p0  = pgB * 8;

    f32x4_t acc[4][4];
#pragma unroll
    for (int i = 0; i < 4; i++)
#pragma unroll
        for (int j = 0; j < 4; j++) acc[i][j] = {0.f, 0.f, 0.f, 0.f};

    // staging prefetch registers
    uint4  aw[4];            // A: 4 x 16B chunks of bf16 W
    uint4  xw[4];            // B (XT==ushort)
    float4 xf[4][2];         // B (XT==float)

    // ---- prologue: issue loads for K-chunk 0 ----
#pragma unroll
    for (int s = 0; s < 4; s++) {
        int u = tid + s * 256;
        int m = u >> 3, kg = u & 7;
        aw[s] = *(const uint4*)&Wb[(size_t)(oB + m) * 256 + kg * 8];
    }
#pragma unroll
    for (int i = 0; i < 4; i++) {
        int c = kgB * 4 + i;
        if constexpr (sizeof(XT) == 4) {
            const float4* s = (const float4*)&Xb[(size_t)c * HWN + pB + p0];
            xf[i][0] = s[0]; xf[i][1] = s[1];
        } else {
            xw[i] = *(const uint4*)&Xb[(size_t)c * HWN + pB + p0];
        }
    }

    for (int kt = 0; kt < 4; kt++) {
        // ---- write phase: staged regs -> LDS ----
#pragma unroll
        for (int s = 0; s < 4; s++) {
            int u = tid + s * 256;
            int m = u >> 3, kg = u & 7;
            *(uint4*)&Al[m * 72 + kg * 8] = aw[s];
        }
        ushort r[4][8];
#pragma unroll
        for (int i = 0; i < 4; i++) {
            if constexpr (sizeof(XT) == 4) {
                float4 x0 = xf[i][0], x1 = xf[i][1];
                r[i][0] = f2bf(x0.x); r[i][1] = f2bf(x0.y);
                r[i][2] = f2bf(x0.z); r[i][3] = f2bf(x0.w);
                r[i][4] = f2bf(x1.x); r[i][5] = f2bf(x1.y);
                r[i][6] = f2bf(x1.z); r[i][7] = f2bf(x1.w);
            } else {
                uint4 u = xw[i];
                r[i][0] = u.x & 0xffff; r[i][1] = u.x >> 16;
                r[i][2] = u.y & 0xffff; r[i][3] = u.y >> 16;
                r[i][4] = u.z & 0xffff; r[i][5] = u.z >> 16;
                r[i][6] = u.w & 0xffff; r[i][7] = u.w >> 16;
            }
        }
        {
            int g   = kgB >> 1;
            int sub = (kgB & 1) * 4;
#pragma unroll
            for (int j = 0; j < 8; j++) {
                int n = p0 + j;
                ushort4 col = make_ushort4(r[0][j], r[1][j], r[2][j], r[3][j]);
                *(ushort4*)&Bl[n * 72 + ((g ^ (pgB & 7)) << 3) + sub] = col;
            }
        }
        __syncthreads();

        // ---- issue next K-chunk's loads (land during MFMA + barrier) ----
        if (kt < 3) {
            int kc = (kt + 1) * 64;
#pragma unroll
            for (int s = 0; s < 4; s++) {
                int u = tid + s * 256;
                int m = u >> 3, kg = u & 7;
                aw[s] = *(const uint4*)&Wb[(size_t)(oB + m) * 256 + kc + kg * 8];
            }
#pragma unroll
            for (int i = 0; i < 4; i++) {
                int c = kc + kgB * 4 + i;
                if constexpr (sizeof(XT) == 4) {
                    const float4* s = (const float4*)&Xb[(size_t)c * HWN + pB + p0];
                    xf[i][0] = s[0]; xf[i][1] = s[1];
                } else {
                    xw[i] = *(const uint4*)&Xb[(size_t)c * HWN + pB + p0];
                }
            }
        }

        // ---- MFMA phase ----
#pragma unroll
        for (int ks = 0; ks < 2; ks++) {
            bf16x8_t af[4], bf[4];
#pragma unroll
            for (int i = 0; i < 4; i++)
                af[i] = *(const bf16x8_t*)&Al[(wm + i * 16 + ln) * 72 + ks * 32 + qd * 8];
#pragma unroll
            for (int j = 0; j < 4; j++) {
                int n = wn + j * 16 + ln;
                int g = ks * 4 + qd;
                bf[j] = *(const bf16x8_t*)&Bl[n * 72 + ((g ^ ((n >> 3) & 7)) << 3)];
            }
#pragma unroll
            for (int i = 0; i < 4; i++)
#pragma unroll
                for (int j = 0; j < 4; j++)
                    acc[i][j] = __builtin_amdgcn_mfma_f32_16x16x32_bf16(
                        af[i], bf[j], acc[i][j], 0, 0, 0);
        }
        __syncthreads();
    }

#pragma unroll
    for (int i = 0; i < 4; i++) {
#pragma unroll
        for (int j = 0; j < 4; j++) {
#pragma unroll
            for (int rr = 0; rr < 4; rr++) {
                int o = oB + wm + i * 16 + qd * 4 + rr;
                int p = pB + wn + j * 16 + ln;
                if constexpr (sizeof(YT) == 4)
                    Yb[(size_t)o * HWN + p] = acc[i][j][rr];
                else
                    Yb[(size_t)o * HWN + p] = f2bf(acc[i][j][rr]);
            }
        }
    }
}

// ---------------------------------------------------------------------------
// Kernel 3: windowed attention v3.  One wave per (window, head).
// S^T = K.Q^T via MFMA (error-compensated bf16 split, bias rides in C);
// softmax mostly in-lane; PV via MFMA.  OUT may alias VP.
// ---------------------------------------------------------------------------
__global__ __launch_bounds__(64, 4) void win_attn(
    const float* __restrict__ QP, const float* __restrict__ KP,
    const ushort* VP, ushort* OUT, const float* __restrict__ biasF)
{
    __shared__ char smem[10240];
    ushort* ql = (ushort*)smem;                  // [64][40] phase 1 (Q split)
    ushort* kq = (ushort*)(smem + 5120);         // [64][40] phase 1 (K split)
    ushort* pl = (ushort*)smem;                  // [64][72] phase 2 (P bf16)
    float*  ol = (float*)smem;                   // [64][36] phase 3 (O f32)

    int bx   = blockIdx.x;
    int head = bx & 7;
    int win  = bx >> 3;
    int wc   = win & 31;
    int wr   = (win >> 5) & 31;
    int b    = win >> 10;

    int n   = threadIdx.x;
    int ws1 = n >> 3, ws2 = n & 7;
    int pos = (wr * 8 + ws1) * 256 + wc * 8 + ws2;

    const float*  qb = QP + ((size_t)(b * 64 + head * 8)) * HWN + pos;
    const float*  kb = KP + ((size_t)(b * 64 + head * 8)) * HWN + pos;
    const ushort* vbase = VP + ((size_t)(b * 256 + head * 32)) * HWN
                             + (size_t)(wr * 8) * 256 + wc * 8;
    ushort*       ob = OUT + ((size_t)(b * 256 + head * 32)) * HWN + pos;

    // ---- stage q (scaled, hi/lo split) and k (hi/lo split) as bf16 rows ----
    uint qh[4], qlw[4], kh[4], klw[4];
#pragma unroll
    for (int d = 0; d < 4; d++) {
        float q0 = qb[(size_t)(2 * d)     * HWN] * SCALE;
        float q1 = qb[(size_t)(2 * d + 1) * HWN] * SCALE;
        ushort qh0 = f2bf(q0), qh1 = f2bf(q1);
        ushort ql0 = f2bf(q0 - bf2f(qh0)), ql1 = f2bf(q1 - bf2f(qh1));
        qh[d]  = (uint)qh0 | ((uint)qh1 << 16);
        qlw[d] = (uint)ql0 | ((uint)ql1 << 16);
        float k0 = kb[(size_t)(2 * d)     * HWN];
        float k1 = kb[(size_t)(2 * d + 1) * HWN];
        ushort kh0 = f2bf(k0), kh1 = f2bf(k1);
        ushort kl0 = f2bf(k0 - bf2f(kh0)), kl1 = f2bf(k1 - bf2f(kh1));
        kh[d]  = (uint)kh0 | ((uint)kh1 << 16);
        klw[d] = (uint)kl0 | ((uint)kl1 << 16);
    }
    uint4 z4 = make_uint4(0u, 0u, 0u, 0u);
    uint4 qhv = make_uint4(qh[0], qh[1], qh[2], qh[3]);
    uint4 qlv = make_uint4(qlw[0], qlw[1], qlw[2], qlw[3]);
    uint4 khv = make_uint4(kh[0], kh[1], kh[2], kh[3]);
    uint4 klv = make_uint4(klw[0], klw[1], klw[2], klw[3]);
    // Q row: [qhi | qlo | qhi | 0]; K row: [khi | khi | klo | 0]
    *(uint4*)&ql[n * 40 +  0] = qhv;
    *(uint4*)&ql[n * 40 +  8] = qlv;
    *(uint4*)&ql[n * 40 + 16] = qhv;
    *(uint4*)&ql[n * 40 + 24] = z4;
    *(uint4*)&kq[n * 40 +  0] = khv;
    *(uint4*)&kq[n * 40 +  8] = khv;
    *(uint4*)&kq[n * 40 + 16] = klv;
    *(uint4*)&kq[n * 40 + 24] = z4;
    __syncthreads();

    int ln = n & 15, qd = n >> 4;

    // ---- S^T = K.Q^T + bias via MFMA (C init = bias fragment) ----
    f32x4_t sacc[4][4];
    const float* bfr = biasF + (size_t)head * 4096;   // [tile][lane][r]
#pragma unroll
    for (int i = 0; i < 4; i++)
#pragma unroll
        for (int j = 0; j < 4; j++)
            sacc[i][j] = *(const f32x4_t*)&bfr[((i * 4 + j) * 64 + n) * 4];

    bf16x8_t kf[4];
#pragma unroll
    for (int i = 0; i < 4; i++)
        kf[i] = *(const bf16x8_t*)&kq[(16 * i + ln) * 40 + qd * 8];
#pragma unroll
    for (int j = 0; j < 4; j++) {
        bf16x8_t qf = *(const bf16x8_t*)&ql[(16 * j + ln) * 40 + qd * 8];
#pragma unroll
        for (int i = 0; i < 4; i++)
            sacc[i][j] = __builtin_amdgcn_mfma_f32_16x16x32_bf16(
                kf[i], qf, sacc[i][j], 0, 0, 0);
    }
    // lane holds S^T[m][n'] + bias, m = 16i + qd*4 + r, n' = 16j + ln

    // ---- softmax over m: 15 in-lane fmax/adds + shfl_xor(16,32) per j ----
    float rs[4];
#pragma unroll
    for (int j = 0; j < 4; j++) {
        float m0 = sacc[0][j][0];
#pragma unroll
        for (int i = 0; i < 4; i++)
#pragma unroll
            for (int r = 0; r < 4; r++) m0 = fmaxf(m0, sacc[i][j][r]);
        m0 = fmaxf(m0, __shfl_xor(m0, 16));
        m0 = fmaxf(m0, __shfl_xor(m0, 32));
        float s0 = 0.f;
#pragma unroll
        for (int i = 0; i < 4; i++)
#pragma unroll
            for (int r = 0; r < 4; r++) {
                float e = __expf(sacc[i][j][r] - m0);
                sacc[i][j][r] = e;
                s0 += e;
            }
        s0 += __shfl_xor(s0, 16);
        s0 += __shfl_xor(s0, 32);
        rs[j] = 1.f / s0;
    }

    __syncthreads();   // ql/kq fully consumed; reuse smem as pl

    // ---- P^T -> pl[n'][m] bf16 (16x ds_write_b64) ----
#pragma unroll
    for (int i = 0; i < 4; i++)
#pragma unroll
        for (int j = 0; j < 4; j++) {
            uint lo = (uint)f2bf(sacc[i][j][0] * rs[j])
                    | ((uint)f2bf(sacc[i][j][1] * rs[j]) << 16);
            uint hi = (uint)f2bf(sacc[i][j][2] * rs[j])
                    | ((uint)f2bf(sacc[i][j][3] * rs[j]) << 16);
            *(uint2*)&pl[(16 * j + ln) * 72 + 16 * i + qd * 4] = make_uint2(lo, hi);
        }
    __syncthreads();

    // ---- PV via MFMA: O[n][d] = sum_m P[n][m] V[m][d] ----
    f32x4_t acc[4][2];
#pragma unroll
    for (int i = 0; i < 4; i++)
#pragma unroll
        for (int j = 0; j < 2; j++) acc[i][j] = {0.f, 0.f, 0.f, 0.f};

#pragma unroll
    for (int kc = 0; kc < 2; kc++) {
        bf16x8_t af[4], bfv[2];
#pragma unroll
        for (int i = 0; i < 4; i++)
            af[i] = *(const bf16x8_t*)&pl[(16 * i + ln) * 72 + kc * 32 + qd * 8];
#pragma unroll
        for (int j = 0; j < 2; j++) {
            // B[d=16j+ln][k=m]: 8 consecutive tokens, contiguous 16B in global
            const ushort* vp8 = vbase + (size_t)(16 * j + ln) * HWN
                                      + (kc * 4 + qd) * 256;
            uint4 u = *(const uint4*)vp8;
            bfv[j] = *(const bf16x8_t*)&u;
        }
#pragma unroll
        for (int i = 0; i < 4; i++)
#pragma unroll
            for (int j = 0; j < 2; j++)
                acc[i][j] = __builtin_amdgcn_mfma_f32_16x16x32_bf16(
                    af[i], bfv[j], acc[i][j], 0, 0, 0);
    }
    __syncthreads();   // pl fully consumed; reuse smem as ol

    // ---- C-layout -> LDS -> per-lane rows, coalesced stores ----
#pragma unroll
    for (int i = 0; i < 4; i++)
#pragma unroll
        for (int j = 0; j < 2; j++)
#pragma unroll
            for (int r = 0; r < 4; r++)
                ol[(16 * i + qd * 4 + r) * 36 + j * 16 + ln] = acc[i][j][r];
    __syncthreads();

#pragma unroll
    for (int c = 0; c < 8; c++) {
        float4 o4 = *(const float4*)&ol[n * 36 + c * 4];
        ob[(size_t)(c * 4 + 0) * HWN] = f2bf(o4.x);
        ob[(size_t)(c * 4 + 1) * HWN] = f2bf(o4.y);
        ob[(size_t)(c * 4 + 2) * HWN] = f2bf(o4.z);
        ob[(size_t)(c * 4 + 3) * HWN] = f2bf(o4.w);
    }
}

// ---------------------------------------------------------------------------
// Kernel 4: reflect-pad + 8x8 depthwise conv + BN.  bf16 in/out, fp32 math.
// R4b: bf16 LDS tile + 8-wide x 4-tall thread strips.
// ---------------------------------------------------------------------------
__global__ __launch_bounds__(256, 5) void dwconv_bn(
    const ushort* __restrict__ A, const float* __restrict__ DW,
    const float* __restrict__ gamma, const float* __restrict__ beta,
    const float* __restrict__ mean, const float* __restrict__ var,
    ushort* __restrict__ O)
{
    __shared__ ushort til[39 * 272];

    int c  = blockIdx.y;
    int b  = blockIdx.z;
    int tY = blockIdx.x * 32;
    int tid = threadIdx.x;

    const ushort* Ab = A + ((size_t)(b * 256 + c)) * HWN;

    // ---- tile load: 39 rows x 34 uint4-chunks of 8 bf16 ----
    for (int li = tid; li < 39 * 34; li += 256) {
        int yr = li / 34;
        int ck = li - yr * 34;
        int iy = tY - 3 + yr;
        uint4 u = make_uint4(0u, 0u, 0u, 0u);
        if (iy >= 0 && iy <= 256) {
            int sy = (iy == 256) ? 254 : iy;
            const ushort* row = Ab + sy * 256;
            if (ck >= 1 && ck <= 32) {
                u = *(const uint4*)&row[ck * 8 - 8];   // ix = 8ck-8..8ck-1, aligned
            } else if (ck == 33) {
                u.x = (uint)row[254];                  // ix==256 -> 254; 257.. -> 0
            }
            // ck == 0: ix -8..-1 -> zeros
        }
        *(uint4*)&til[yr * 272 + ck * 8] = u;
    }

    // ---- weights: uniform address -> scalar loads ----
    float w[64];
#pragma unroll
    for (int i = 0; i < 16; i++)
        *(float4*)&w[i * 4] = *(const float4*)&DW[c * 64 + i * 4];

    __syncthreads();

    float inv = gamma[c] * rsqrtf(var[c] + 1e-5f);
    float add = fmaf(-mean[c], inv, beta[c]);

    int xg = tid & 31;       // 32 x-groups * 8 wide = 256
    int yg = tid >> 5;       // 8  y-groups * 4 tall = 32
    int xo = xg * 8;
    int yb = yg * 4;

    float acc[4][8];
#pragma unroll
    for (int j = 0; j < 4; j++)
#pragma unroll
        for (int p = 0; p < 8; p++) acc[j][p] = 0.f;

#pragma unroll
    for (int r = 0; r < 11; r++) {
        const uint4* rp = (const uint4*)&til[(yb + r) * 272 + xo];
        uint4 a0 = rp[0], a1 = rp[1], a2 = rp[2];
        uint u[12] = {a0.x, a0.y, a0.z, a0.w,
                      a1.x, a1.y, a1.z, a1.w,
                      a2.x, a2.y, a2.z, a2.w};
        float vals[16];
#pragma unroll
        for (int t = 2; t < 10; t++) {
            vals[2 * (t - 2)]     = __uint_as_float(u[t] << 16);
            vals[2 * (t - 2) + 1] = __uint_as_float(u[t] & 0xffff0000u);
        }
        int jlo = (r - 7 < 0) ? 0 : r - 7;
        int jhi = (r < 3) ? r : 3;
#pragma unroll
        for (int j = jlo; j <= jhi; j++) {
            const float* wr = &w[(r - j) * 8];
#pragma unroll
            for (int kx = 0; kx < 8; kx++) {
                float wt = wr[kx];
#pragma unroll
                for (int p = 0; p < 8; p++)
                    acc[j][p] = fmaf(vals[1 + p + kx], wt, acc[j][p]);
            }
        }
    }

    ushort* Ob = O + ((size_t)(b * 256 + c)) * HWN + (tY + yb) * 256 + xo;
#pragma unroll
    for (int j = 0; j < 4; j++) {
        uint4 st;
        st.x = (uint)f2bf(fmaf(acc[j][0], inv, add))
             | ((uint)f2bf(fmaf(acc[j][1], inv, add)) << 16);
        st.y = (uint)f2bf(fmaf(acc[j][2], inv, add))
             | ((uint)f2bf(fmaf(acc[j][3], inv, add)) << 16);
        st.z = (uint)f2bf(fmaf(acc[j][4], inv, add))
             | ((uint)f2bf(fmaf(acc[j][5], inv, add)) << 16);
        st.w = (uint)f2bf(fmaf(acc[j][6], inv, add))
             | ((uint)f2bf(fmaf(acc[j][7], inv, add)) << 16);
        *(uint4*)&Ob[j * 256] = st;
    }
}

// ---------------------------------------------------------------------------
// Workspace (192 MiB, exactly full): qp f32 | kp f32 | vp bf16 (aliased by
// attn out) | dwo bf16.
// Scratch in d_out (dead regions, each consumed before the final GEMM
// overwrites it):  biasF = out tail (consumed by win_attn);
//                  Wvb   = out head (consumed by gemm #1);
// pwb packs into the qp region AFTER win_attn (qp dead by then).
// ---------------------------------------------------------------------------
extern "C" void kernel_launch(void* const* d_in, const int* in_sizes, int n_in,
                              void* d_out, int out_size, void* d_ws, size_t ws_size,
                              hipStream_t stream)
{
    (void)in_sizes; (void)n_in; (void)ws_size;

    const float* q    = (const float*)d_in[0];
    const float* v    = (const float*)d_in[1];
    const float* Wq   = (const float*)d_in[2];
    const float* Wk   = (const float*)d_in[3];
    const float* Wv   = (const float*)d_in[4];
    const float* bt   = (const float*)d_in[5];
    const float* dw   = (const float*)d_in[6];
    const float* gam  = (const float*)d_in[7];
    const float* bet  = (const float*)d_in[8];
    const float* mean = (const float*)d_in[9];
    const float* var  = (const float*)d_in[10];
    const float* pw   = (const float*)d_in[11];
    const int*   ri   = (const int*)d_in[12];
    float* out = (float*)d_out;

    float*  qp  = (float*)d_ws;
    float*  kp  = qp + (size_t)2 * 64 * HWN;
    ushort* vp  = (ushort*)(kp + (size_t)2 * 64 * HWN);
    ushort* ao  = vp;                          // alias, see win_attn comment
    ushort* dwo = vp + (size_t)2 * 256 * HWN;
    float*  biasF = out + (size_t)out_size - 32768;
    ushort* wvb = (ushort*)out;                // out head, dead until final GEMM
    ushort* pwb = (ushort*)qp;                 // qp region, dead after win_attn

    bias_pre<<<128, 256, 0, stream>>>(bt, ri, biasF);
    pack_w<<<64, 256, 0, stream>>>(Wv, wvb);
    conv1x1_qk<<<512, 256, 0, stream>>>(q, Wq, Wk, qp, kp);
    gemm256<float, ushort><<<dim3(512, 2, 2), 256, 0, stream>>>(v, wvb, vp);
    win_attn<<<16384, 64, 0, stream>>>(qp, kp, vp, ao, biasF);
    pack_w<<<64, 256, 0, stream>>>(pw, pwb);
    dwconv_bn<<<dim3(8, 256, 2), 256, 0, stream>>>(ao, dw, gam, bet, mean, var, dwo);
    gemm256<ushort, float><<<dim3(512, 2, 2), 256, 0, stream>>>(dwo, pwb, out);
}

// Round 6
// 494.931 us; speedup vs baseline: 1.3233x; 1.3233x over previous
//
#include <hip/hip_runtime.h>
#include <cstddef>

#define HWN 65536              // 256*256
#define SCALE 0.35355339059327373f

typedef __bf16 bf16x8_t __attribute__((ext_vector_type(8)));
typedef float  f32x4_t  __attribute__((ext_vector_type(4)));

static __device__ __forceinline__ ushort f2bf(float f) {
    uint u = __float_as_uint(f);
    u = u + 0x7fffu + ((u >> 16) & 1u);   // RNE
    return (ushort)(u >> 16);
}
static __device__ __forceinline__ float bf2f(ushort b) {
    return __uint_as_float(((uint)b) << 16);
}

// ---------------------------------------------------------------------------
// Kernel 0: expand bias_table via rel_index into MFMA C-fragment order:
// biasF[h][tile=i*4+j][lane][r] so win_attn can init its QK accumulators
// directly from 16 coalesced float4 loads (bias rides in the MFMA C input).
// ---------------------------------------------------------------------------
__global__ __launch_bounds__(256) void bias_pre(
    const float* __restrict__ bt, const int* __restrict__ ri,
    float* __restrict__ biasF)
{
    int g = blockIdx.x * 256 + threadIdx.x;   // 0..32767
    int h    = g >> 12;
    int rem  = g & 4095;
    int tile = rem >> 8;            // i*4 + j
    int lane = (rem >> 2) & 63;
    int r    = rem & 3;
    int i = tile >> 2, j = tile & 3;
    int qd = lane >> 4, ln = lane & 15;
    int m = i * 16 + qd * 4 + r;
    int n = j * 16 + ln;
    biasF[g] = bt[ri[n * 64 + m] * 8 + h];
}

// ---------------------------------------------------------------------------
// Kernel 1 (R6): fused qp = Wq.x, kp = Wk.qp via MFMA.
// R5 post-mortem: VALU version was grid-limited (2 waves/SIMD) and serial;
// 166us vs a ~16us HBM floor.  This is matmul-shaped work on an idle MFMA
// pipe.  Per 128-pixel tile: stage X as error-compensated bf16 hi/lo
// (win_attn's proven trick), GEMM1 = 3-term split MFMA (WhXh+WhXl+WlXh ~ f32
// precision), re-split qp into the same LDS buffers, GEMM2 for kp (kp is
// pixel-local in qp, so the fusion needs no global round-trip).
// LDS 72KB -> 2 blocks/CU; 96 MFMA/wave; staging-bound.
// ---------------------------------------------------------------------------
__global__ __launch_bounds__(256) void qk_mfma(
    const float* __restrict__ X, const float* __restrict__ WQ,
    const float* __restrict__ WK, float* __restrict__ QP,
    float* __restrict__ KP)
{
    __shared__ ushort Bh[128 * 72];      // [p][k] hi  (X, then qp)
    __shared__ ushort Blo[128 * 72];     // [p][k] lo
    __shared__ ushort Wh[2][64 * 72];    // Wq,Wk hi  [o][c]
    __shared__ ushort Wl[2][64 * 72];    // Wq,Wk lo

    int b   = blockIdx.y;
    int pB  = blockIdx.x * 128;
    int tid = threadIdx.x;

    const float* Xb = X + (size_t)b * 64 * HWN;
    float* Qb = QP + (size_t)b * 64 * HWN;
    float* Kb = KP + (size_t)b * 64 * HWN;

    int wv = tid >> 6, lane = tid & 63;
    int wn = wv * 32;                 // wave owns 32 px (N); full M=64
    int qd = lane >> 4, ln = lane & 15;

    int kgB = tid >> 4;               // 16 k-groups of 4 channels
    int pgB = tid & 15;               // 16 px-groups of 8
    int p0  = pgB * 8;

    // ---- stage W (hi/lo split), linear [o][c] rows, stride 72 ----
#pragma unroll
    for (int mat = 0; mat < 2; mat++) {
        const float* Wsrc = mat ? WK : WQ;
#pragma unroll
        for (int s = 0; s < 2; s++) {
            int u = tid + s * 256;            // 0..511
            int m = u >> 3, kg = u & 7;
            const float4* src = (const float4*)&Wsrc[m * 64 + kg * 8];
            float4 w0 = src[0], w1 = src[1];
            float wf[8] = {w0.x, w0.y, w0.z, w0.w, w1.x, w1.y, w1.z, w1.w};
            uint4 ph, pl;
            uint* php = (uint*)&ph; uint* plp = (uint*)&pl;
#pragma unroll
            for (int e = 0; e < 4; e++) {
                ushort h0 = f2bf(wf[2*e]),   h1 = f2bf(wf[2*e+1]);
                ushort l0 = f2bf(wf[2*e]   - bf2f(h0));
                ushort l1 = f2bf(wf[2*e+1] - bf2f(h1));
                php[e] = (uint)h0 | ((uint)h1 << 16);
                plp[e] = (uint)l0 | ((uint)l1 << 16);
            }
            *(uint4*)&Wh[mat][m * 72 + kg * 8] = ph;
            *(uint4*)&Wl[mat][m * 72 + kg * 8] = pl;
        }
    }

    // ---- stage X tile (hi/lo), transposed to [p][c] with gemm256 swizzle ----
    {
        ushort rh[4][8], rl[4][8];
#pragma unroll
        for (int i = 0; i < 4; i++) {
            int c = kgB * 4 + i;
            const float4* s = (const float4*)&Xb[(size_t)c * HWN + pB + p0];
            float4 x0 = s[0], x1 = s[1];
            float xv[8] = {x0.x, x0.y, x0.z, x0.w, x1.x, x1.y, x1.z, x1.w};
#pragma unroll
            for (int e = 0; e < 8; e++) {
                ushort h = f2bf(xv[e]);
                rh[i][e] = h;
                rl[i][e] = f2bf(xv[e] - bf2f(h));
            }
        }
        int g   = kgB >> 1;
        int sub = (kgB & 1) * 4;
#pragma unroll
        for (int j = 0; j < 8; j++) {
            int n = p0 + j;
            int off = n * 72 + ((g ^ (pgB & 7)) << 3) + sub;
            *(ushort4*)&Bh[off]  = make_ushort4(rh[0][j], rh[1][j], rh[2][j], rh[3][j]);
            *(ushort4*)&Blo[off] = make_ushort4(rl[0][j], rl[1][j], rl[2][j], rl[3][j]);
        }
    }
    __syncthreads();

    // ---- GEMM1: qp = Wq . x  (3-term split) ----
    f32x4_t acc1[4][2];
#pragma unroll
    for (int i = 0; i < 4; i++)
#pragma unroll
        for (int j = 0; j < 2; j++) acc1[i][j] = {0.f, 0.f, 0.f, 0.f};

#pragma unroll
    for (int t = 0; t < 3; t++) {
        const ushort* A = (t == 2) ? Wl[0] : Wh[0];
        const ushort* B = (t == 1) ? Blo   : Bh;
#pragma unroll
        for (int ks = 0; ks < 2; ks++) {
            bf16x8_t af[4];
#pragma unroll
            for (int i = 0; i < 4; i++)
                af[i] = *(const bf16x8_t*)&A[(i * 16 + ln) * 72 + ks * 32 + qd * 8];
#pragma unroll
            for (int j = 0; j < 2; j++) {
                int n = wn + j * 16 + ln;
                bf16x8_t bfj = *(const bf16x8_t*)
                    &B[n * 72 + (((ks * 4 + qd) ^ ((n >> 3) & 7)) << 3)];
#pragma unroll
                for (int i = 0; i < 4; i++)
                    acc1[i][j] = __builtin_amdgcn_mfma_f32_16x16x32_bf16(
                        af[i], bfj, acc1[i][j], 0, 0, 0);
            }
        }
    }
    __syncthreads();   // all waves done reading X from Bh/Blo

    // ---- re-split qp into Bh/Blo as [p][k=o] (same swizzle) ----
#pragma unroll
    for (int i = 0; i < 4; i++) {
        int g   = i * 2 + (qd >> 1);      // col group of o = i*16 + qd*4
        int sub = (qd & 1) * 4;
#pragma unroll
        for (int j = 0; j < 2; j++) {
            int n = wn + j * 16 + ln;
            int off = n * 72 + ((g ^ ((n >> 3) & 7)) << 3) + sub;
            ushort h[4], l[4];
#pragma unroll
            for (int r = 0; r < 4; r++) {
                float v = acc1[i][j][r];
                h[r] = f2bf(v);
                l[r] = f2bf(v - bf2f(h[r]));
            }
            *(uint2*)&Bh[off]  = make_uint2((uint)h[0] | ((uint)h[1] << 16),
                                            (uint)h[2] | ((uint)h[3] << 16));
            *(uint2*)&Blo[off] = make_uint2((uint)l[0] | ((uint)l[1] << 16),
                                            (uint)l[2] | ((uint)l[3] << 16));
        }
    }
    __syncthreads();

    // ---- GEMM2: kp = Wk . qp  (3-term split) ----
    f32x4_t acc2[4][2];
#pragma unroll
    for (int i = 0; i < 4; i++)
#pragma unroll
        for (int j = 0; j < 2; j++) acc2[i][j] = {0.f, 0.f, 0.f, 0.f};

#pragma unroll
    for (int t = 0; t < 3; t++) {
        const ushort* A = (t == 2) ? Wl[1] : Wh[1];
        const ushort* B = (t == 1) ? Blo   : Bh;
#pragma unroll
        for (int ks = 0; ks < 2; ks++) {
            bf16x8_t af[4];
#pragma unroll
            for (int i = 0; i < 4; i++)
                af[i] = *(const bf16x8_t*)&A[(i * 16 + ln) * 72 + ks * 32 + qd * 8];
#pragma unroll
            for (int j = 0; j < 2; j++) {
                int n = wn + j * 16 + ln;
                bf16x8_t bfj = *(const bf16x8_t*)
                    &B[n * 72 + (((ks * 4 + qd) ^ ((n >> 3) & 7)) << 3)];
#pragma unroll
                for (int i = 0; i < 4; i++)
                    acc2[i][j] = __builtin_amdgcn_mfma_f32_16x16x32_bf16(
                        af[i], bfj, acc2[i][j], 0, 0, 0);
            }
        }
    }

    // ---- epilogue: store qp, kp f32 planar ----
#pragma unroll
    for (int i = 0; i < 4; i++) {
#pragma unroll
        for (int j = 0; j < 2; j++) {
            int p = pB + wn + j * 16 + ln;
#pragma unroll
            for (int r = 0; r < 4; r++) {
                int o = i * 16 + qd * 4 + r;
                Qb[(size_t)o * HWN + p] = acc1[i][j][r];
                Kb[(size_t)o * HWN + p] = acc2[i][j][r];
            }
        }
    }
}

// ---------------------------------------------------------------------------
// Kernel 2: 256->256 channel GEMM via bf16 MFMA (reverted to R4: the R5
// register-prefetch variant raised VGPR and cut blocks/CU -> +40us).
// ---------------------------------------------------------------------------
template <typename XT, typename YT>
__global__ __launch_bounds__(256) void gemm256(
    const XT* __restrict__ X, const float* __restrict__ W, YT* __restrict__ Y)
{
    __shared__ ushort Al[128 * 72];   // [m][k], stride 72 bf16
    __shared__ ushort Bl[128 * 72];   // [n][k], swizzled 16B groups

    int b   = blockIdx.z;
    int oB  = blockIdx.y * 128;
    int pB  = blockIdx.x * 128;
    int tid = threadIdx.x;

    const XT* Xb = X + (size_t)b * 256 * HWN;
    YT*       Yb = Y + (size_t)b * 256 * HWN;

    int wv = tid >> 6, lane = tid & 63;
    int wm = (wv >> 1) * 64, wn = (wv & 1) * 64;
    int qd = lane >> 4, ln = lane & 15;

    int kgB = tid >> 4;
    int pgB = tid & 15;
    int p0  = pgB * 8;

    f32x4_t acc[4][4];
#pragma unroll
    for (int i = 0; i < 4; i++)
#pragma unroll
        for (int j = 0; j < 4; j++) acc[i][j] = {0.f, 0.f, 0.f, 0.f};

    for (int kc = 0; kc < 256; kc += 64) {
#pragma unroll
        for (int s = 0; s < 4; s++) {
            int u = tid + s * 256;
            int m = u >> 3, kg = u & 7;
            const float4* src = (const float4*)&W[(oB + m) * 256 + kc + kg * 8];
            float4 w0 = src[0], w1 = src[1];
            uint4 pk;
            pk.x = f2bf(w0.x) | ((uint)f2bf(w0.y) << 16);
            pk.y = f2bf(w0.z) | ((uint)f2bf(w0.w) << 16);
            pk.z = f2bf(w1.x) | ((uint)f2bf(w1.y) << 16);
            pk.w = f2bf(w1.z) | ((uint)f2bf(w1.w) << 16);
            *(uint4*)&Al[m * 72 + kg * 8] = pk;
        }
        ushort r[4][8];
#pragma unroll
        for (int i = 0; i < 4; i++) {
            int c = kc + kgB * 4 + i;
            if constexpr (sizeof(XT) == 4) {
                const float4* s = (const float4*)&Xb[(size_t)c * HWN + pB + p0];
                float4 x0 = s[0], x1 = s[1];
                r[i][0] = f2bf(x0.x); r[i][1] = f2bf(x0.y);
                r[i][2] = f2bf(x0.z); r[i][3] = f2bf(x0.w);
                r[i][4] = f2bf(x1.x); r[i][5] = f2bf(x1.y);
                r[i][6] = f2bf(x1.z); r[i][7] = f2bf(x1.w);
            } else {
                uint4 u = *(const uint4*)&Xb[(size_t)c * HWN + pB + p0];
                r[i][0] = u.x & 0xffff; r[i][1] = u.x >> 16;
                r[i][2] = u.y & 0xffff; r[i][3] = u.y >> 16;
                r[i][4] = u.z & 0xffff; r[i][5] = u.z >> 16;
                r[i][6] = u.w & 0xffff; r[i][7] = u.w >> 16;
            }
        }
        {
            int g   = kgB >> 1;
            int sub = (kgB & 1) * 4;
#pragma unroll
            for (int j = 0; j < 8; j++) {
                int n = p0 + j;
                ushort4 col = make_ushort4(r[0][j], r[1][j], r[2][j], r[3][j]);
                *(ushort4*)&Bl[n * 72 + ((g ^ (pgB & 7)) << 3) + sub] = col;
            }
        }
        __syncthreads();

#pragma unroll
        for (int ks = 0; ks < 2; ks++) {
            bf16x8_t af[4], bf[4];
#pragma unroll
            for (int i = 0; i < 4; i++)
                af[i] = *(const bf16x8_t*)&Al[(wm + i * 16 + ln) * 72 + ks * 32 + qd * 8];
#pragma unroll
            for (int j = 0; j < 4; j++) {
                int n = wn + j * 16 + ln;
                int g = ks * 4 + qd;
                bf[j] = *(const bf16x8_t*)&Bl[n * 72 + ((g ^ ((n >> 3) & 7)) << 3)];
            }
#pragma unroll
            for (int i = 0; i < 4; i++)
#pragma unroll
                for (int j = 0; j < 4; j++)
                    acc[i][j] = __builtin_amdgcn_mfma_f32_16x16x32_bf16(
                        af[i], bf[j], acc[i][j], 0, 0, 0);
        }
        __syncthreads();
    }

#pragma unroll
    for (int i = 0; i < 4; i++) {
#pragma unroll
        for (int j = 0; j < 4; j++) {
#pragma unroll
            for (int rr = 0; rr < 4; rr++) {
                int o = oB + wm + i * 16 + qd * 4 + rr;
                int p = pB + wn + j * 16 + ln;
                if constexpr (sizeof(YT) == 4)
                    Yb[(size_t)o * HWN + p] = acc[i][j][rr];
                else
                    Yb[(size_t)o * HWN + p] = f2bf(acc[i][j][rr]);
            }
        }
    }
}

// ---------------------------------------------------------------------------
// Kernel 3: windowed attention v3.  One wave per (window, head).
// S^T = K.Q^T via MFMA (error-compensated bf16 split, bias rides in C);
// softmax mostly in-lane; PV via MFMA.  OUT may alias VP.
// ---------------------------------------------------------------------------
__global__ __launch_bounds__(64, 4) void win_attn(
    const float* __restrict__ QP, const float* __restrict__ KP,
    const ushort* VP, ushort* OUT, const float* __restrict__ biasF)
{
    __shared__ char smem[10240];
    ushort* ql = (ushort*)smem;                  // [64][40] phase 1 (Q split)
    ushort* kq = (ushort*)(smem + 5120);         // [64][40] phase 1 (K split)
    ushort* pl = (ushort*)smem;                  // [64][72] phase 2 (P bf16)
    float*  ol = (float*)smem;                   // [64][36] phase 3 (O f32)

    int bx   = blockIdx.x;
    int head = bx & 7;
    int win  = bx >> 3;
    int wc   = win & 31;
    int wr   = (win >> 5) & 31;
    int b    = win >> 10;

    int n   = threadIdx.x;
    int ws1 = n >> 3, ws2 = n & 7;
    int pos = (wr * 8 + ws1) * 256 + wc * 8 + ws2;

    const float*  qb = QP + ((size_t)(b * 64 + head * 8)) * HWN + pos;
    const float*  kb = KP + ((size_t)(b * 64 + head * 8)) * HWN + pos;
    const ushort* vbase = VP + ((size_t)(b * 256 + head * 32)) * HWN
                             + (size_t)(wr * 8) * 256 + wc * 8;
    ushort*       ob = OUT + ((size_t)(b * 256 + head * 32)) * HWN + pos;

    // ---- stage q (scaled, hi/lo split) and k (hi/lo split) as bf16 rows ----
    uint qh[4], qlw[4], kh[4], klw[4];
#pragma unroll
    for (int d = 0; d < 4; d++) {
        float q0 = qb[(size_t)(2 * d)     * HWN] * SCALE;
        float q1 = qb[(size_t)(2 * d + 1) * HWN] * SCALE;
        ushort qh0 = f2bf(q0), qh1 = f2bf(q1);
        ushort ql0 = f2bf(q0 - bf2f(qh0)), ql1 = f2bf(q1 - bf2f(qh1));
        qh[d]  = (uint)qh0 | ((uint)qh1 << 16);
        qlw[d] = (uint)ql0 | ((uint)ql1 << 16);
        float k0 = kb[(size_t)(2 * d)     * HWN];
        float k1 = kb[(size_t)(2 * d + 1) * HWN];
        ushort kh0 = f2bf(k0), kh1 = f2bf(k1);
        ushort kl0 = f2bf(k0 - bf2f(kh0)), kl1 = f2bf(k1 - bf2f(kh1));
        kh[d]  = (uint)kh0 | ((uint)kh1 << 16);
        klw[d] = (uint)kl0 | ((uint)kl1 << 16);
    }
    uint4 z4 = make_uint4(0u, 0u, 0u, 0u);
    uint4 qhv = make_uint4(qh[0], qh[1], qh[2], qh[3]);
    uint4 qlv = make_uint4(qlw[0], qlw[1], qlw[2], qlw[3]);
    uint4 khv = make_uint4(kh[0], kh[1], kh[2], kh[3]);
    uint4 klv = make_uint4(klw[0], klw[1], klw[2], klw[3]);
    // Q row: [qhi | qlo | qhi | 0]; K row: [khi | khi | klo | 0]
    *(uint4*)&ql[n * 40 +  0] = qhv;
    *(uint4*)&ql[n * 40 +  8] = qlv;
    *(uint4*)&ql[n * 40 + 16] = qhv;
    *(uint4*)&ql[n * 40 + 24] = z4;
    *(uint4*)&kq[n * 40 +  0] = khv;
    *(uint4*)&kq[n * 40 +  8] = khv;
    *(uint4*)&kq[n * 40 + 16] = klv;
    *(uint4*)&kq[n * 40 + 24] = z4;
    __syncthreads();

    int ln = n & 15, qd = n >> 4;

    // ---- S^T = K.Q^T + bias via MFMA (C init = bias fragment) ----
    f32x4_t sacc[4][4];
    const float* bfr = biasF + (size_t)head * 4096;   // [tile][lane][r]
#pragma unroll
    for (int i = 0; i < 4; i++)
#pragma unroll
        for (int j = 0; j < 4; j++)
            sacc[i][j] = *(const f32x4_t*)&bfr[((i * 4 + j) * 64 + n) * 4];

    bf16x8_t kf[4];
#pragma unroll
    for (int i = 0; i < 4; i++)
        kf[i] = *(const bf16x8_t*)&kq[(16 * i + ln) * 40 + qd * 8];
#pragma unroll
    for (int j = 0; j < 4; j++) {
        bf16x8_t qf = *(const bf16x8_t*)&ql[(16 * j + ln) * 40 + qd * 8];
#pragma unroll
        for (int i = 0; i < 4; i++)
            sacc[i][j] = __builtin_amdgcn_mfma_f32_16x16x32_bf16(
                kf[i], qf, sacc[i][j], 0, 0, 0);
    }
    // lane holds S^T[m][n'] + bias, m = 16i + qd*4 + r, n' = 16j + ln

    // ---- softmax over m: 15 in-lane fmax/adds + shfl_xor(16,32) per j ----
    float rs[4];
#pragma unroll
    for (int j = 0; j < 4; j++) {
        float m0 = sacc[0][j][0];
#pragma unroll
        for (int i = 0; i < 4; i++)
#pragma unroll
            for (int r = 0; r < 4; r++) m0 = fmaxf(m0, sacc[i][j][r]);
        m0 = fmaxf(m0, __shfl_xor(m0, 16));
        m0 = fmaxf(m0, __shfl_xor(m0, 32));
        float s0 = 0.f;
#pragma unroll
        for (int i = 0; i < 4; i++)
#pragma unroll
            for (int r = 0; r < 4; r++) {
                float e = __expf(sacc[i][j][r] - m0);
                sacc[i][j][r] = e;
                s0 += e;
            }
        s0 += __shfl_xor(s0, 16);
        s0 += __shfl_xor(s0, 32);
        rs[j] = 1.f / s0;
    }

    __syncthreads();   // ql/kq fully consumed; reuse smem as pl

    // ---- P^T -> pl[n'][m] bf16 (16x ds_write_b64) ----
#pragma unroll
    for (int i = 0; i < 4; i++)
#pragma unroll
        for (int j = 0; j < 4; j++) {
            uint lo = (uint)f2bf(sacc[i][j][0] * rs[j])
                    | ((uint)f2bf(sacc[i][j][1] * rs[j]) << 16);
            uint hi = (uint)f2bf(sacc[i][j][2] * rs[j])
                    | ((uint)f2bf(sacc[i][j][3] * rs[j]) << 16);
            *(uint2*)&pl[(16 * j + ln) * 72 + 16 * i + qd * 4] = make_uint2(lo, hi);
        }
    __syncthreads();

    // ---- PV via MFMA: O[n][d] = sum_m P[n][m] V[m][d] ----
    f32x4_t acc[4][2];
#pragma unroll
    for (int i = 0; i < 4; i++)
#pragma unroll
        for (int j = 0; j < 2; j++) acc[i][j] = {0.f, 0.f, 0.f, 0.f};

#pragma unroll
    for (int kc = 0; kc < 2; kc++) {
        bf16x8_t af[4], bfv[2];
#pragma unroll
        for (int i = 0; i < 4; i++)
            af[i] = *(const bf16x8_t*)&pl[(16 * i + ln) * 72 + kc * 32 + qd * 8];
#pragma unroll
        for (int j = 0; j < 2; j++) {
            // B[d=16j+ln][k=m]: 8 consecutive tokens, contiguous 16B in global
            const ushort* vp8 = vbase + (size_t)(16 * j + ln) * HWN
                                      + (kc * 4 + qd) * 256;
            uint4 u = *(const uint4*)vp8;
            bfv[j] = *(const bf16x8_t*)&u;
        }
#pragma unroll
        for (int i = 0; i < 4; i++)
#pragma unroll
            for (int j = 0; j < 2; j++)
                acc[i][j] = __builtin_amdgcn_mfma_f32_16x16x32_bf16(
                    af[i], bfv[j], acc[i][j], 0, 0, 0);
    }
    __syncthreads();   // pl fully consumed; reuse smem as ol

    // ---- C-layout -> LDS -> per-lane rows, coalesced stores ----
#pragma unroll
    for (int i = 0; i < 4; i++)
#pragma unroll
        for (int j = 0; j < 2; j++)
#pragma unroll
            for (int r = 0; r < 4; r++)
                ol[(16 * i + qd * 4 + r) * 36 + j * 16 + ln] = acc[i][j][r];
    __syncthreads();

#pragma unroll
    for (int c = 0; c < 8; c++) {
        float4 o4 = *(const float4*)&ol[n * 36 + c * 4];
        ob[(size_t)(c * 4 + 0) * HWN] = f2bf(o4.x);
        ob[(size_t)(c * 4 + 1) * HWN] = f2bf(o4.y);
        ob[(size_t)(c * 4 + 2) * HWN] = f2bf(o4.z);
        ob[(size_t)(c * 4 + 3) * HWN] = f2bf(o4.w);
    }
}

// ---------------------------------------------------------------------------
// Kernel 4: reflect-pad + 8x8 depthwise conv + BN.  bf16 in/out, fp32 math.
// R4b: bf16 LDS tile + 8-wide x 4-tall thread strips.
// ---------------------------------------------------------------------------
__global__ __launch_bounds__(256, 5) void dwconv_bn(
    const ushort* __restrict__ A, const float* __restrict__ DW,
    const float* __restrict__ gamma, const float* __restrict__ beta,
    const float* __restrict__ mean, const float* __restrict__ var,
    ushort* __restrict__ O)
{
    __shared__ ushort til[39 * 272];

    int c  = blockIdx.y;
    int b  = blockIdx.z;
    int tY = blockIdx.x * 32;
    int tid = threadIdx.x;

    const ushort* Ab = A + ((size_t)(b * 256 + c)) * HWN;

    // ---- tile load: 39 rows x 34 uint4-chunks of 8 bf16 ----
    for (int li = tid; li < 39 * 34; li += 256) {
        int yr = li / 34;
        int ck = li - yr * 34;
        int iy = tY - 3 + yr;
        uint4 u = make_uint4(0u, 0u, 0u, 0u);
        if (iy >= 0 && iy <= 256) {
            int sy = (iy == 256) ? 254 : iy;
            const ushort* row = Ab + sy * 256;
            if (ck >= 1 && ck <= 32) {
                u = *(const uint4*)&row[ck * 8 - 8];   // ix = 8ck-8..8ck-1, aligned
            } else if (ck == 33) {
                u.x = (uint)row[254];                  // ix==256 -> 254; 257.. -> 0
            }
            // ck == 0: ix -8..-1 -> zeros
        }
        *(uint4*)&til[yr * 272 + ck * 8] = u;
    }

    // ---- weights: uniform address -> scalar loads ----
    float w[64];
#pragma unroll
    for (int i = 0; i < 16; i++)
        *(float4*)&w[i * 4] = *(const float4*)&DW[c * 64 + i * 4];

    __syncthreads();

    float inv = gamma[c] * rsqrtf(var[c] + 1e-5f);
    float add = fmaf(-mean[c], inv, beta[c]);

    int xg = tid & 31;       // 32 x-groups * 8 wide = 256
    int yg = tid >> 5;       // 8  y-groups * 4 tall = 32
    int xo = xg * 8;
    int yb = yg * 4;

    float acc[4][8];
#pragma unroll
    for (int j = 0; j < 4; j++)
#pragma unroll
        for (int p = 0; p < 8; p++) acc[j][p] = 0.f;

#pragma unroll
    for (int r = 0; r < 11; r++) {
        const uint4* rp = (const uint4*)&til[(yb + r) * 272 + xo];
        uint4 a0 = rp[0], a1 = rp[1], a2 = rp[2];
        uint u[12] = {a0.x, a0.y, a0.z, a0.w,
                      a1.x, a1.y, a1.z, a1.w,
                      a2.x, a2.y, a2.z, a2.w};
        float vals[16];
#pragma unroll
        for (int t = 2; t < 10; t++) {
            vals[2 * (t - 2)]     = __uint_as_float(u[t] << 16);
            vals[2 * (t - 2) + 1] = __uint_as_float(u[t] & 0xffff0000u);
        }
        int jlo = (r - 7 < 0) ? 0 : r - 7;
        int jhi = (r < 3) ? r : 3;
#pragma unroll
        for (int j = jlo; j <= jhi; j++) {
            const float* wr = &w[(r - j) * 8];
#pragma unroll
            for (int kx = 0; kx < 8; kx++) {
                float wt = wr[kx];
#pragma unroll
                for (int p = 0; p < 8; p++)
                    acc[j][p] = fmaf(vals[1 + p + kx], wt, acc[j][p]);
            }
        }
    }

    ushort* Ob = O + ((size_t)(b * 256 + c)) * HWN + (tY + yb) * 256 + xo;
#pragma unroll
    for (int j = 0; j < 4; j++) {
        uint4 st;
        st.x = (uint)f2bf(fmaf(acc[j][0], inv, add))
             | ((uint)f2bf(fmaf(acc[j][1], inv, add)) << 16);
        st.y = (uint)f2bf(fmaf(acc[j][2], inv, add))
             | ((uint)f2bf(fmaf(acc[j][3], inv, add)) << 16);
        st.z = (uint)f2bf(fmaf(acc[j][4], inv, add))
             | ((uint)f2bf(fmaf(acc[j][5], inv, add)) << 16);
        st.w = (uint)f2bf(fmaf(acc[j][6], inv, add))
             | ((uint)f2bf(fmaf(acc[j][7], inv, add)) << 16);
        *(uint4*)&Ob[j * 256] = st;
    }
}

// ---------------------------------------------------------------------------
// Workspace (192 MiB): qp f32 | kp f32 | vp bf16 (aliased by attn out) | dwo.
// biasF (128 KB) lives in the tail of d_out — dead until the final GEMM,
// which overwrites it after win_attn has consumed it.
// ---------------------------------------------------------------------------
extern "C" void kernel_launch(void* const* d_in, const int* in_sizes, int n_in,
                              void* d_out, int out_size, void* d_ws, size_t ws_size,
                              hipStream_t stream)
{
    (void)in_sizes; (void)n_in; (void)ws_size;

    const float* q    = (const float*)d_in[0];
    const float* v    = (const float*)d_in[1];
    const float* Wq   = (const float*)d_in[2];
    const float* Wk   = (const float*)d_in[3];
    const float* Wv   = (const float*)d_in[4];
    const float* bt   = (const float*)d_in[5];
    const float* dw   = (const float*)d_in[6];
    const float* gam  = (const float*)d_in[7];
    const float* bet  = (const float*)d_in[8];
    const float* mean = (const float*)d_in[9];
    const float* var  = (const float*)d_in[10];
    const float* pw   = (const float*)d_in[11];
    const int*   ri   = (const int*)d_in[12];
    float* out = (float*)d_out;

    float*  qp  = (float*)d_ws;
    float*  kp  = qp + (size_t)2 * 64 * HWN;
    ushort* vp  = (ushort*)(kp + (size_t)2 * 64 * HWN);
    ushort* ao  = vp;                          // alias, see win_attn comment
    ushort* dwo = vp + (size_t)2 * 256 * HWN;
    float*  biasF = out + (size_t)out_size - 32768;

    bias_pre<<<128, 256, 0, stream>>>(bt, ri, biasF);
    qk_mfma<<<dim3(512, 2), 256, 0, stream>>>(q, Wq, Wk, qp, kp);
    gemm256<float, ushort><<<dim3(512, 2, 2), 256, 0, stream>>>(v, Wv, vp);
    win_attn<<<16384, 64, 0, stream>>>(qp, kp, vp, ao, biasF);
    dwconv_bn<<<dim3(8, 256, 2), 256, 0, stream>>>(ao, dw, gam, bet, mean, var, dwo);
    gemm256<ushort, float><<<dim3(512, 2, 2), 256, 0, stream>>>(dwo, pw, out);
}